// Round 4
// baseline (944.260 us; speedup 1.0000x reference)
//
#include <hip/hip_runtime.h>
#include <stdint.h>

#define N4K 4096
#define BIGF 1e30f
#define POIS 0xAAAAAAAAu

// ---- full-wave shift-by-1 toward higher lanes; lane0 receives `oldv`
__device__ __forceinline__ float dpp_shr1(float oldv, float src) {
  int r = __builtin_amdgcn_update_dpp(__float_as_int(oldv), __float_as_int(src),
                                      0x138 /*wave_shr:1*/, 0xF, 0xF, false);
  return __int_as_float(r);
}

__device__ __forceinline__ void st_bnd(unsigned* p, float v) {
  __hip_atomic_store(p, __float_as_uint(v), __ATOMIC_RELAXED,
                     __HIP_MEMORY_SCOPE_AGENT);
}
__device__ __forceinline__ unsigned ld_bnd(const unsigned* p) {
  return __hip_atomic_load((unsigned*)p, __ATOMIC_RELAXED,
                           __HIP_MEMORY_SCOPE_AGENT);
}

// =============== K0: poison the handoff buffer ===============
__global__ void k_poison(unsigned* __restrict__ bnd) {
  bnd[(size_t)blockIdx.x * 256 + threadIdx.x] = POIS;
}

// =============== K1: cost matrix ct[j][i] = ||x_i - y_j|| ===============
// 128x128 tile per block, 256 threads, K=64 single pass, fp32 vector FMA
// (no fp32-input MFMA on CDNA4; bf16 cast deferred until verify passes).
__global__ __launch_bounds__(256) void k_cost(const float* __restrict__ X,
                                              const float* __restrict__ Y,
                                              float* __restrict__ ct) {
  __shared__ __align__(16) float ys[64][132];
  __shared__ __align__(16) float xs[64][132];
  __shared__ float ynm[128];
  __shared__ float xnm[128];
  const int tid = threadIdx.x;
  const int jt = blockIdx.y << 7;
  const int it = blockIdx.x << 7;
#pragma unroll
  for (int r = 0; r < 32; ++r) {
    int e = tid + (r << 8);
    int row = e >> 6, k = e & 63;
    ys[k][row] = Y[(size_t)(jt + row) * 64 + k];
    xs[k][row] = X[(size_t)(it + row) * 64 + k];
  }
  __syncthreads();
  {
    int r = tid & 127;
    float s = 0.f;
    if (tid < 128) {
#pragma unroll
      for (int k = 0; k < 64; ++k) { float v = ys[k][r]; s = fmaf(v, v, s); }
      ynm[r] = s;
    } else {
#pragma unroll
      for (int k = 0; k < 64; ++k) { float v = xs[k][r]; s = fmaf(v, v, s); }
      xnm[r] = s;
    }
  }
  __syncthreads();
  const int tx = tid & 15, ty = tid >> 4;
  float acc[8][8];
#pragma unroll
  for (int r = 0; r < 8; ++r)
#pragma unroll
    for (int c = 0; c < 8; ++c) acc[r][c] = 0.f;
#pragma unroll 4
  for (int k = 0; k < 64; ++k) {
    float a[8], b[8];
    *(float4*)&a[0] = *(const float4*)&ys[k][(ty << 2)];
    *(float4*)&a[4] = *(const float4*)&ys[k][64 + (ty << 2)];
    *(float4*)&b[0] = *(const float4*)&xs[k][(tx << 2)];
    *(float4*)&b[4] = *(const float4*)&xs[k][64 + (tx << 2)];
#pragma unroll
    for (int r = 0; r < 8; ++r)
#pragma unroll
      for (int c = 0; c < 8; ++c) acc[r][c] = fmaf(a[r], b[c], acc[r][c]);
  }
#pragma unroll
  for (int r = 0; r < 8; ++r) {
    const int lr = ((r & 4) << 4) + (ty << 2) + (r & 3);
    const float yn = ynm[lr];
    float o[8];
#pragma unroll
    for (int c = 0; c < 8; ++c) {
      const int lc = ((c & 4) << 4) + (tx << 2) + (c & 3);
      float sq = yn + xnm[lc] - 2.f * acc[r][c];
      o[c] = sqrtf(fmaxf(sq, 1e-12f));
    }
    float* dst = ct + (size_t)(jt + lr) * N4K + it;
    *(float4*)(dst + (tx << 2)) = make_float4(o[0], o[1], o[2], o[3]);
    *(float4*)(dst + 64 + (tx << 2)) = make_float4(o[4], o[5], o[6], o[7]);
  }
}

// =============== K2: pipelined wavefront DP ===============
// 64 blocks x 1 wave; strip s = rows i in [64s,64s+64); lane l at step u
// computes cell (i=64s+l, j=u-l).  D = min3(up,left,diag+c)+c with
// eprev = n1 + c_next computed off the dependency chain
// (chain: dpp -> v_min3 -> v_add  ~= 12 cy/step).
//
// Cost ring tl: UN-skewed (j,i) layout, 256 rows (4 chunks) + 16 mirror rows.
//   value c[i0+col][j] at float index ((j&255)<<6) + col.
//   read (step u, lane l): row (u-l)&255, col l -> per-batch vaddr
//     tl + (((nub-l)&255)<<6) + l, then 16x ds_read offset:s*256 (imm).
//     Rows base+s up to 270 land in the mirror region (rows 256..271 copy
//     rows 0..15).  Banks: col=l uniform-per-lane -> 2-way, free.
//   write: wgroup(m) writes j-rows [64m,64m+64) at slot (m&3)*64 -- slot-
//     aligned, no wrap, vaddr + offset:r*256 (imm). col=lane -> 2-way, free.
//   staging: gload(m) = 64 coalesced b32 loads (col-slice per lane) one
//     chunk ahead of wgroup; all ordering is plain dataflow (compiler-
//     tracked vmcnt/lgkmcnt, no manual waits, no LDS-DMA aliasing hazard).
// Ring slots: at iter n reads touch slots (n-1,n,n+1)&3, write slot (n+2-1
// staged->written (n+1)&3)... write slot (n+1)&3 disjoint from read slot
// (n-1)&3 only under 4-slot ring with writes 1 ahead: reads j<=64n+79,
// write rows [64(n+1),64(n+1)+63] -> distinct ✓.
// Chunk 64 (u in [4096,4159]): valid lanes read j in [4033,4095] = group 63
// (still intact); invalid lanes read stale/uninit values -- harmless: their
// dn is overridden (PRED) and the one eprev that survives to a first-valid
// step is BIGF + real c[i][0] by construction.
template <bool DO_NXTQ, bool PRED>
__device__ __forceinline__ void run_iter(const float* tl, const float* topb,
                                         int ubb, float (&curc)[16],
                                         float4 (&curq)[4], float (&nxtc)[16],
                                         float4 (&nxtq)[4], float& d,
                                         float& eprev, int lane, bool is00,
                                         bool doSt, unsigned* bdst) {
  const int nub = ubb + 16;
  const float* ba = tl + (((nub - lane) & 255) << 6) + lane;
#pragma unroll
  for (int s = 0; s < 16; ++s) nxtc[s] = ba[s << 6];
  if (DO_NXTQ) {
#pragma unroll
    for (int q = 0; q < 4; ++q)
      nxtq[q] = *(const float4*)&topb[(nub + (q << 2)) & 127];
  }
  float g0 = 0.f, g1 = 0.f, g2v = 0.f, g3 = 0.f;
#pragma unroll
  for (int s = 0; s < 16; ++s) {
    const int u = ubb + s;
    const float cst = curc[s];
    const float cnx = (s < 15) ? curc[s + 1] : nxtc[0];
    const float4 qq = curq[s >> 2];
    const float tqe = ((s & 3) == 0)   ? qq.x
                      : ((s & 3) == 1) ? qq.y
                      : ((s & 3) == 2) ? qq.z
                                       : qq.w;
    float n1 = dpp_shr1(tqe, d);  // up; lane0 <- top boundary
    // D = min3(up, left, diag+c) + c ; eprev = diag+c computed off-chain
    float dn = fminf(fminf(n1, d), eprev) + cst;
    if (PRED) {
      if (is00 && u == 0) dn = cst;              // D[0][0] = c[0][0]
      if ((unsigned)(u - lane) > 4095u) dn = d;  // freeze invalid columns
    }
    eprev = n1 + cnx;
    d = dn;
    if ((s & 3) == 0) g0 = d;
    if ((s & 3) == 1) g1 = d;
    if ((s & 3) == 2) g2v = d;
    if ((s & 3) == 3) {
      g3 = d;
      if (doSt) {  // lane 63 of a producing strip: publish bottom row
        const int jb = u - 66;
        if (PRED) {
          if ((unsigned)(jb + 0) <= 4095u) st_bnd(bdst + (jb + 0), g0);
          if ((unsigned)(jb + 1) <= 4095u) st_bnd(bdst + (jb + 1), g1);
          if ((unsigned)(jb + 2) <= 4095u) st_bnd(bdst + (jb + 2), g2v);
          if ((unsigned)(jb + 3) <= 4095u) st_bnd(bdst + (jb + 3), g3);
        } else {
          st_bnd(bdst + (jb + 0), g0);
          st_bnd(bdst + (jb + 1), g1);
          st_bnd(bdst + (jb + 2), g2v);
          st_bnd(bdst + (jb + 3), g3);
        }
      }
    }
  }
}

__global__ __launch_bounds__(64) void k_dp(const float* __restrict__ ct,
                                           unsigned* __restrict__ bnd,
                                           float* __restrict__ out) {
  __shared__ __align__(16) float tl[272 * 64];  // 68KB: 4-chunk ring + mirror
  __shared__ __align__(16) float topb[128];     // 2-chunk top-boundary ring
  const int lane = threadIdx.x;
  const int b = (int)blockIdx.x;
  const int strip = ((b & 7) << 3) | (b >> 3);  // consecutive strips same XCD
  const int i0 = strip << 6;
  const bool hasTop = (strip != 0);
  const bool doSt = (strip != 63) && (lane == 63);
  const bool is00 = (strip == 0) && (lane == 0);
  const unsigned* bsrc = bnd + (size_t)(hasTop ? strip - 1 : 0) * N4K;
  unsigned* bdst = bnd + (size_t)strip * N4K;

  float gst[64];  // one 64-row j-group in flight (column slice per lane)

  auto gload = [&](int m) {  // coalesced: 256B per b32 instruction
    const float* gb = ct + (size_t)(m << 6) * N4K + i0 + lane;
#pragma unroll
    for (int r = 0; r < 64; ++r) gst[r] = gb[(size_t)r * N4K];
  };
  auto wgroup = [&](int m) {  // slot-aligned, imm-offset writes, 2-way banks
    float* wb = tl + ((m & 3) << 12) + lane;
#pragma unroll
    for (int r = 0; r < 64; ++r) wb[r << 6] = gst[r];
    if ((m & 3) == 0) {  // mirror rows 0..15 -> 256..271 (read-batch wrap)
      float* wm = tl + (256 << 6) + lane;
#pragma unroll
      for (int r = 0; r < 16; ++r) wm[r << 6] = gst[r];
    }
  };

  // ---- prologue: groups 0,1 staged; top boundary chunk 0 polled
  gload(0);
  wgroup(0);
  gload(1);
  unsigned tvP = 0, tvN = 0;
  if (hasTop) {
    tvP = ld_bnd(bsrc + lane);
    int gc = 0;
    while (__any((int)(tvP == POIS)) && ++gc < (1 << 16))
      tvP = ld_bnd(bsrc + lane);
    topb[lane] = __uint_as_float(tvP);
  } else {
    topb[lane] = BIGF;  // strip 0: top boundary +inf forever (both slots)
    topb[64 + lane] = BIGF;
  }

  float cA[16], cB[16];
  float4 qA[4], qB[4];
  {
    const float* ba0 = tl + (((0 - lane) & 255) << 6) + lane;
#pragma unroll
    for (int s = 0; s < 16; ++s) cA[s] = ba0[s << 6];
  }
#pragma unroll
  for (int q = 0; q < 4; ++q) qA[q] = *(const float4*)&topb[(q << 2)];

  float d = BIGF, eprev = BIGF;

  auto pollQ = [&](int q, int n) {  // finalize quarter q of chunk n's topb
    int gc = 0;
    while (__any((int)((lane >> 4) == q && tvP == POIS)) && ++gc < (1 << 16))
      tvP = ld_bnd(bsrc + (n << 6) + lane);
    if ((lane >> 4) == q) topb[((n & 1) << 6) + lane] = __uint_as_float(tvP);
  };

#pragma unroll 1
  for (int n = 0; n <= 64; ++n) {
    const bool doTv = hasTop && (n + 1 <= 63);
    if (doTv) tvN = ld_bnd(bsrc + ((n + 1) << 6) + lane);  // early issue
    if (n + 1 <= 63) wgroup(n + 1);  // writes group loaded last iter
    if (n + 2 <= 63) gload(n + 2);   // refill gst (WAR handled by compiler)
    const bool doQ = hasTop && (n <= 63);
    const int ub = n << 6;
    if (doQ) pollQ(1, n);
    if (n == 0 || n == 64) {
      run_iter<true, true>(tl, topb, ub + 0, cA, qA, cB, qB, d, eprev, lane,
                           is00, doSt, bdst);
      if (doQ) pollQ(2, n);
      run_iter<true, true>(tl, topb, ub + 16, cB, qB, cA, qA, d, eprev, lane,
                           is00, doSt, bdst);
      if (doQ) pollQ(3, n);
      run_iter<true, true>(tl, topb, ub + 32, cA, qA, cB, qB, d, eprev, lane,
                           is00, doSt, bdst);
      run_iter<false, true>(tl, topb, ub + 48, cB, qB, cA, qA, d, eprev, lane,
                            is00, doSt, bdst);
    } else {
      run_iter<true, false>(tl, topb, ub + 0, cA, qA, cB, qB, d, eprev, lane,
                            is00, doSt, bdst);
      if (doQ) pollQ(2, n);
      run_iter<true, false>(tl, topb, ub + 16, cB, qB, cA, qA, d, eprev, lane,
                            is00, doSt, bdst);
      if (doQ) pollQ(3, n);
      run_iter<true, false>(tl, topb, ub + 32, cA, qA, cB, qB, d, eprev, lane,
                            is00, doSt, bdst);
      run_iter<false, false>(tl, topb, ub + 48, cB, qB, cA, qA, d, eprev, lane,
                             is00, doSt, bdst);
    }
    if (doTv) {  // quarter 0 of chunk n+1, then carry tvN -> tvP
      int gc = 0;
      while (__any((int)((lane >> 4) == 0 && tvN == POIS)) && ++gc < (1 << 16))
        tvN = ld_bnd(bsrc + ((n + 1) << 6) + lane);
      if ((lane >> 4) == 0)
        topb[(((n + 1) & 1) << 6) + lane] = __uint_as_float(tvN);
      tvP = tvN;
    }
#pragma unroll
    for (int q = 0; q < 4; ++q)  // pre-read next chunk's first top quads
      qA[q] = *(const float4*)&topb[((ub + 64) + (q << 2)) & 127];
  }
  if (strip == 63 && lane == 63) out[0] = d;  // D[4095][4095]
}

extern "C" void kernel_launch(void* const* d_in, const int* in_sizes, int n_in,
                              void* d_out, int out_size, void* d_ws,
                              size_t ws_size, hipStream_t stream) {
  (void)in_sizes; (void)n_in; (void)out_size; (void)ws_size;
  const float* X = (const float*)d_in[0];
  const float* Y = (const float*)d_in[1];
  float* out = (float*)d_out;
  float* ct = (float*)d_ws;  // 64 MB
  unsigned* bnd = (unsigned*)((char*)d_ws + (size_t)N4K * N4K * sizeof(float));

  k_poison<<<1024, 256, 0, stream>>>(bnd);  // 1 MB handoff buffer
  k_cost<<<dim3(32, 32), 256, 0, stream>>>(X, Y, ct);
  k_dp<<<64, 64, 0, stream>>>(ct, bnd, out);
}